// Round 15
// baseline (43.378 us; speedup 1.0000x reference)
//
#include <hip/hip_runtime.h>
#include <hip/hip_bf16.h>
#include <stdint.h>

// Problem constants
#define D       256
#define KCB     1024
#define HW      1024        // 32*32
#define NROWS   32768       // 32*32*32
#define TOTAL   8388608     // 32*256*32*32
#define SCL     256.0f      // emb pre-scale: keeps S*e out of e4m3 denormal range
#define ISCL    (1.0f / 256.0f)

// ws layout (bytes)
#define WS_EMBF8 0          // 512 frags x 512B = 262144 : fp8 codes (x256), B-frag order
#define WS_CINIT 262144     // 1024*4 : 256*(1 - 0.5*|e|^2)
#define WS_KEY   266240     // 32768*4 : packed argmin key per z-row
#define WS_PART  397312     // 1024*4 : per-(WG,wm) loss partials

typedef float f32x4 __attribute__((ext_vector_type(4)));
typedef unsigned int u32x2 __attribute__((ext_vector_type(2)));

union F8x8 { unsigned u[2]; long l; u32x2 v; };
union FU   { float f; unsigned u; };

// ---------------- K1: fp8 frag-pack (x256) + scaled c_init ------------------
// Waves 0..511: frag (cb,kb): lane l holds S*emb[cb*16+(l&15)][kb*32+(l>>4)*8+j]
// as byte j of an 8-byte fp8 frag. Same slot mapping as A in k_dist, so the
// MFMA dot is correct under any consistent hardware k-permutation.
__global__ __launch_bounds__(256) void k_prep(const float* __restrict__ emb,
                                              unsigned char* __restrict__ ws) {
  const int t = threadIdx.x;
  const int lane = t & 63;
  const int W = blockIdx.x * 4 + (t >> 6);   // 0..1535
  if (W < 512) {
    const int cb = W >> 3, kb = W & 7;
    const int code = cb * 16 + (lane & 15);
    const int d0   = kb * 32 + (lane >> 4) * 8;
    const float4 a = *reinterpret_cast<const float4*>(emb + code * D + d0);
    const float4 b = *reinterpret_cast<const float4*>(emb + code * D + d0 + 4);
    unsigned lo = 0, hi = 0;
    lo = (unsigned)__builtin_amdgcn_cvt_pk_fp8_f32(a.x * SCL, a.y * SCL, (int)lo, false);
    lo = (unsigned)__builtin_amdgcn_cvt_pk_fp8_f32(a.z * SCL, a.w * SCL, (int)lo, true);
    hi = (unsigned)__builtin_amdgcn_cvt_pk_fp8_f32(b.x * SCL, b.y * SCL, (int)hi, false);
    hi = (unsigned)__builtin_amdgcn_cvt_pk_fp8_f32(b.z * SCL, b.w * SCL, (int)hi, true);
    u32x2 p; p[0] = lo; p[1] = hi;
    *reinterpret_cast<u32x2*>(ws + WS_EMBF8 + (size_t)(W * 64 + lane) * 8) = p;
  } else {
    const int code = W - 512;                // 0..1023
    const float4 v = *reinterpret_cast<const float4*>(emb + code * D + lane * 4);
    float ss = v.x * v.x + v.y * v.y + v.z * v.z + v.w * v.w;
    #pragma unroll
    for (int m = 1; m < 64; m <<= 1) ss += __shfl_xor(ss, m, 64);
    if (lane == 0)
      *reinterpret_cast<float*>(ws + WS_CINIT + code * 4) = SCL * (1.0f - 0.5f * ss);
  }
}

// ---------------- K2: dist + argmin + loss-partial ---------------------------
// 512 WGs x 256 thr (4 waves), 2x2 wave split: wave (wm,wn) = 32 rows x 512
// codes. Live set ~110 VGPR <= the 128 cap of launch_bounds(256,2) -> NO
// scratch spill (R13/R14 lesson: the cap is 256/waves_per_SIMD). Barrier-free
// main loop; one tiny kbuf barrier at the end. acc' = 256*(1+z.e-0.5|e|^2)>0
// -> IEEE-bit monotone; key = (bits&~1023)|(1023-code); running max.
#define LOADF(S, CB) do {                                                     \
    const long* _e = reinterpret_cast<const long*>(embf8 + (size_t)(CB) * 4096) + lane; \
    _Pragma("unroll")                                                         \
    for (int kb = 0; kb < 8; ++kb) S[kb] = _e[kb * 64];                       \
  } while (0)

#define COMPUTE(S, CB, CI) do {                                               \
    const float ci = (CI);                                                    \
    f32x4 a0 = {ci, ci, ci, ci}, a1 = {ci, ci, ci, ci};                       \
    _Pragma("unroll")                                                         \
    for (int kb = 0; kb < 8; ++kb) {                                          \
      a0 = __builtin_amdgcn_mfma_f32_16x16x32_fp8_fp8(afrag[0][kb], S[kb], a0, 0, 0, 0); \
      a1 = __builtin_amdgcn_mfma_f32_16x16x32_fp8_fp8(afrag[1][kb], S[kb], a1, 0, 0, 0); \
    }                                                                         \
    const unsigned base = (unsigned)(1023 - (CB) * 16) - (unsigned)crl;       \
    _Pragma("unroll")                                                         \
    for (int r = 0; r < 4; ++r) {                                             \
      FU f0, f1;                                                              \
      f0.f = a0[r]; f1.f = a1[r];                                             \
      const unsigned k0 = (f0.u & 0xFFFFFC00u) | base;                        \
      const unsigned k1 = (f1.u & 0xFFFFFC00u) | base;                        \
      kmax[0][r] = kmax[0][r] > k0 ? kmax[0][r] : k0;                         \
      kmax[1][r] = kmax[1][r] > k1 ? kmax[1][r] : k1;                         \
    }                                                                         \
  } while (0)

__global__ __launch_bounds__(256, 2) void k_dist(const float* __restrict__ z,
                                                 const unsigned char* __restrict__ embf8,
                                                 const float* __restrict__ c_init,
                                                 unsigned* __restrict__ key_out,
                                                 float* __restrict__ partials) {
  __shared__ unsigned kbuf[64 * 2];          // only LDS: per-row half keys

  const int t    = threadIdx.x;
  const int lane = t & 63;
  const int w    = t >> 6;        // 0..3
  const int wm   = w >> 1;        // 0..1 : 32-row block
  const int wn   = w & 1;         // 0..1 : code half
  const int crl  = lane & 15;
  const int g    = lane >> 4;     // 0..3
  const int row0 = blockIdx.x * 64;
  const int b    = row0 >> 10;
  const int hw0  = row0 & 1023;
  const float* zb = z + (size_t)b * (D * HW) + hw0;

  // ---- Prologue: 32 z-rows -> fp8 A-frags in-register + per-row |z|^2
  long afrag[2][8];
  float zsq[2];
  #pragma unroll
  for (int m = 0; m < 2; ++m) {
    float s2 = 0.f;
    const int rl = wm * 32 + m * 16 + crl;
    #pragma unroll
    for (int kb = 0; kb < 8; ++kb) {
      float v[8];
      #pragma unroll
      for (int j = 0; j < 8; ++j) {
        v[j] = zb[(size_t)(kb * 32 + g * 8 + j) * HW + rl];
        s2 += v[j] * v[j];
      }
      F8x8 p;
      unsigned lo = 0, hi = 0;
      lo = (unsigned)__builtin_amdgcn_cvt_pk_fp8_f32(v[0], v[1], (int)lo, false);
      lo = (unsigned)__builtin_amdgcn_cvt_pk_fp8_f32(v[2], v[3], (int)lo, true);
      hi = (unsigned)__builtin_amdgcn_cvt_pk_fp8_f32(v[4], v[5], (int)hi, false);
      hi = (unsigned)__builtin_amdgcn_cvt_pk_fp8_f32(v[6], v[7], (int)hi, true);
      p.u[0] = lo; p.u[1] = hi;
      afrag[m][kb] = p.l;
    }
    zsq[m] = s2;
  }
  #pragma unroll
  for (int m = 0; m < 2; ++m) {              // sum the 4 g-groups -> full row
    zsq[m] += __shfl_xor(zsq[m], 16, 64);
    zsq[m] += __shfl_xor(zsq[m], 32, 64);
  }

  unsigned kmax[2][4];
  #pragma unroll
  for (int m = 0; m < 2; ++m)
    #pragma unroll
    for (int r = 0; r < 4; ++r) kmax[m][r] = 0u;

  // ---- Main loop: 32 code-blocks (this wave's half), 2-deep prefetch,
  // rolling 2-reg ci prefetch, NO barriers, NO LDS, NO spill.
  {
    const int cb0 = wn * 32;
    long sA[8], sB[8];
    LOADF(sA, cb0);
    float ciA = c_init[cb0 * 16 + crl];
    #pragma unroll
    for (int i = 0; i < 32; i += 2) {
      LOADF(sB, cb0 + i + 1);
      const float ciB = c_init[(cb0 + i + 1) * 16 + crl];
      COMPUTE(sA, cb0 + i, ciA);
      if (i + 2 < 32) {
        LOADF(sA, cb0 + i + 2);
        ciA = c_init[(cb0 + i + 2) * 16 + crl];
      }
      COMPUTE(sB, cb0 + i + 1, ciB);
    }
  }

  // ---- argmax reduce over the 16 col-lanes (codes within half)
  #pragma unroll
  for (int s = 1; s <= 8; s <<= 1)
    #pragma unroll
    for (int m = 0; m < 2; ++m)
      #pragma unroll
      for (int r = 0; r < 4; ++r) {
        const unsigned o = __shfl_xor(kmax[m][r], s, 64);
        kmax[m][r] = kmax[m][r] > o ? kmax[m][r] : o;
      }

  // ---- combine the 2 halves per row via tiny LDS
  if (crl == 0) {
    #pragma unroll
    for (int m = 0; m < 2; ++m)
      #pragma unroll
      for (int r = 0; r < 4; ++r)
        kbuf[(wm * 32 + m * 16 + g * 4 + r) * 2 + wn] = kmax[m][r];
  }
  __syncthreads();

  // wn==0 waves finalize their own 32 rows (zsq is lane-local: row = ..+crl)
  float myloss = 0.f;
  if (wn == 0 && g == 0) {
    #pragma unroll
    for (int m = 0; m < 2; ++m) {
      const int rl = wm * 32 + m * 16 + crl;
      const unsigned k0 = kbuf[rl * 2 + 0], k1 = kbuf[rl * 2 + 1];
      const unsigned km = k0 > k1 ? k0 : k1;
      key_out[row0 + rl] = km;
      FU fu; fu.u = km & 0xFFFFFC00u;        // winner acc' (trunc, positive)
      const float zr = (m == 0) ? zsq[0] : zsq[1];
      myloss += zr - 2.0f * (fu.f * ISCL - 1.0f);
    }
  }
  if (wn == 0) {
    #pragma unroll
    for (int s = 1; s < 64; s <<= 1) myloss += __shfl_xor(myloss, s, 64);
    if (lane == 0) partials[blockIdx.x * 2 + wm] = myloss;
  }
}

// ---------------- K3: gather + transposed coalesced write (R9-verified) -----
__global__ __launch_bounds__(256) void k_combine(const unsigned* __restrict__ keys,
                                                 const float* __restrict__ embf32,
                                                 float* __restrict__ out) {
  __shared__ unsigned char gb[65536];
  __shared__ int idx_l[64];
  const int t = threadIdx.x;
  const int lane = t & 63;
  const int w = t >> 6;
  const int row0 = blockIdx.x * 64;
  const int b = row0 >> 10;
  const int hw0 = row0 & 1023;

  if (t < 64) idx_l[t] = 1023 - (int)(keys[row0 + t] & 1023u);
  __syncthreads();

  const float4* emb4 = reinterpret_cast<const float4*>(embf32);
  #pragma unroll
  for (int i = 0; i < 16; ++i) {
    const int r = w * 16 + i;
    const int k = idx_l[r];
    const float4 v = emb4[(size_t)k * 64 + lane];
    *reinterpret_cast<float4*>(
        &gb[r * 1024 + ((unsigned)(lane * 16) ^ (unsigned)((r & 7) << 4))]) = v;
  }
  __syncthreads();

  const int r = lane;
  const unsigned rsw = (unsigned)((r & 7) << 4);
  float* outb = out + (size_t)b * (D * HW) + (size_t)(hw0 + r);
  #pragma unroll
  for (int i = 0; i < 16; ++i) {
    const int dq = w * 16 + i;
    const f32x4 v = *reinterpret_cast<const f32x4*>(
        &gb[r * 1024 + ((unsigned)(dq * 16) ^ rsw)]);
    #pragma unroll
    for (int q = 0; q < 4; ++q)
      outb[(size_t)(dq * 4 + q) * HW] = v[q];
  }
}

// ---------------- K4: final loss reduce (1024 partials) ---------------------
__global__ __launch_bounds__(256) void k_loss(const float* __restrict__ partials,
                                              float* __restrict__ out_loss) {
  const int t = threadIdx.x;
  float s = partials[t] + partials[t + 256] + partials[t + 512] + partials[t + 768];
  #pragma unroll
  for (int m = 1; m < 64; m <<= 1) s += __shfl_xor(s, m, 64);
  __shared__ float wsum[4];
  if ((t & 63) == 0) wsum[t >> 6] = s;
  __syncthreads();
  if (t == 0)
    out_loss[0] = 1.25f * (wsum[0] + wsum[1] + wsum[2] + wsum[3]) * (1.0f / 8388608.0f);
}

extern "C" void kernel_launch(void* const* d_in, const int* in_sizes, int n_in,
                              void* d_out, int out_size, void* d_ws, size_t ws_size,
                              hipStream_t stream) {
  (void)in_sizes; (void)n_in; (void)out_size; (void)ws_size;
  const float* z   = (const float*)d_in[0];
  const float* emb = (const float*)d_in[1];
  float* out = (float*)d_out;
  unsigned char* ws = (unsigned char*)d_ws;

  k_prep<<<384, 256, 0, stream>>>(emb, ws);
  k_dist<<<512, 256, 0, stream>>>(z, ws + WS_EMBF8,
                                  (const float*)(ws + WS_CINIT),
                                  (unsigned*)(ws + WS_KEY),
                                  (float*)(ws + WS_PART));
  k_combine<<<512, 256, 0, stream>>>((const unsigned*)(ws + WS_KEY), emb, out);
  k_loss<<<1, 256, 0, stream>>>((const float*)(ws + WS_PART), out + TOTAL);
}